// Round 5
// baseline (1453.276 us; speedup 1.0000x reference)
//
#include <hip/hip_runtime.h>
#include <hip/hip_bf16.h>

typedef __attribute__((ext_vector_type(8))) __bf16 bf16x8;
typedef __attribute__((ext_vector_type(4))) float f32x4;

#define F_DIM 512
#define D_DIM 128
#define RPB 128            // rows per bucket (bucket = row >> 7)
#define MAXBUK 1024
#define BIN_CHUNK 8192

__device__ __forceinline__ unsigned short f32_to_bf16_rn(float x) {
    union { float f; unsigned u; } v; v.f = x;
    unsigned u = v.u;
    unsigned rounded = u + 0x7fffu + ((u >> 16) & 1u);
    return (unsigned short)(rounded >> 16);
}
__device__ __forceinline__ float bf16_to_f32(unsigned short u) {
    return __uint_as_float((unsigned)u << 16);
}

// W [512][128] f32 -> Wt [128][512] bf16 (transposed, k-contiguous)
__global__ void wt_kernel(const float* __restrict__ W, unsigned short* __restrict__ Wt) {
    int idx = blockIdx.x * blockDim.x + threadIdx.x;   // 65536 total
    int n = idx >> 9;
    int k = idx & 511;
    Wt[idx] = f32_to_bf16_rn(W[k * D_DIM + n]);
}

// support = relu(feature @ W) -> bf16. 128x128 tile, BK=32, reg-staged +
// LDS double-buffer, one barrier per K-step.
__global__ __launch_bounds__(256) void gemm_relu_pipe(
    const float* __restrict__ A,
    const unsigned short* __restrict__ Bt,
    unsigned short* __restrict__ Sb,
    int Nrows)
{
    __shared__ unsigned short Al[2 * 128 * 40];
    __shared__ unsigned short Bl[2 * 128 * 40];

    const int tid  = threadIdx.x;
    const int wave = tid >> 6;
    const int lane = tid & 63;
    const int g    = lane >> 4;
    const int r16  = lane & 15;
    const int m0   = blockIdx.x * 128;

    const int srow = tid >> 1;
    const int kh   = tid & 1;
    int arow = m0 + srow;
    if (arow >= Nrows) arow = Nrows - 1;
    const float*          aptr = A  + (size_t)arow * F_DIM + kh * 16;
    const unsigned short* bptr = Bt + (size_t)srow * F_DIM + kh * 16;
    const int woff = srow * 40 + kh * 16;

    float4 ar0, ar1, ar2, ar3;
    uint4  br0, br1;

    auto loadAB = [&](int ks) {
        const float4* pa = (const float4*)(aptr + ks * 32);
        ar0 = pa[0]; ar1 = pa[1]; ar2 = pa[2]; ar3 = pa[3];
        const uint4* pb = (const uint4*)(bptr + ks * 32);
        br0 = pb[0]; br1 = pb[1];
    };
    auto storeAB = [&](int buf) {
        union { uint4 q[2]; __bf16 h[16]; } u;
        u.h[0]=(__bf16)ar0.x;  u.h[1]=(__bf16)ar0.y;  u.h[2]=(__bf16)ar0.z;  u.h[3]=(__bf16)ar0.w;
        u.h[4]=(__bf16)ar1.x;  u.h[5]=(__bf16)ar1.y;  u.h[6]=(__bf16)ar1.z;  u.h[7]=(__bf16)ar1.w;
        u.h[8]=(__bf16)ar2.x;  u.h[9]=(__bf16)ar2.y;  u.h[10]=(__bf16)ar2.z; u.h[11]=(__bf16)ar2.w;
        u.h[12]=(__bf16)ar3.x; u.h[13]=(__bf16)ar3.y; u.h[14]=(__bf16)ar3.z; u.h[15]=(__bf16)ar3.w;
        unsigned short* aw = Al + buf * 5120 + woff;
        unsigned short* bw = Bl + buf * 5120 + woff;
        *(uint4*)aw       = u.q[0];
        *(uint4*)(aw + 8) = u.q[1];
        *(uint4*)bw       = br0;
        *(uint4*)(bw + 8) = br1;
    };

    f32x4 acc[2][8];
#pragma unroll
    for (int i = 0; i < 2; ++i)
#pragma unroll
        for (int j = 0; j < 8; ++j) acc[i][j] = (f32x4)0.0f;

    loadAB(0);
    storeAB(0);
    __syncthreads();

#pragma unroll
    for (int ks = 0; ks < 16; ++ks) {
        const int cur = ks & 1;
        if (ks < 15) loadAB(ks + 1);

        const unsigned short* Ab = Al + cur * 5120;
        const unsigned short* Bb = Bl + cur * 5120;
        bf16x8 af0 = *(const bf16x8*)&Ab[(wave * 32 +      r16) * 40 + g * 8];
        bf16x8 af1 = *(const bf16x8*)&Ab[(wave * 32 + 16 + r16) * 40 + g * 8];
#pragma unroll
        for (int nf = 0; nf < 8; ++nf) {
            bf16x8 bf = *(const bf16x8*)&Bb[(nf * 16 + r16) * 40 + g * 8];
            acc[0][nf] = __builtin_amdgcn_mfma_f32_16x16x32_bf16(af0, bf, acc[0][nf], 0, 0, 0);
            acc[1][nf] = __builtin_amdgcn_mfma_f32_16x16x32_bf16(af1, bf, acc[1][nf], 0, 0, 0);
        }

        if (ks < 15) storeAB(cur ^ 1);
        __syncthreads();
    }

#pragma unroll
    for (int mf = 0; mf < 2; ++mf) {
#pragma unroll
        for (int nf = 0; nf < 8; ++nf) {
#pragma unroll
            for (int r = 0; r < 4; ++r) {
                int row = m0 + wave * 32 + mf * 16 + g * 4 + r;
                if (row < Nrows) {
                    float v = acc[mf][nf][r];
                    Sb[(size_t)row * D_DIM + nf * 16 + r16] = f32_to_bf16_rn(v > 0.f ? v : 0.f);
                }
            }
        }
    }
}

// cursor[b] = b * cap
__global__ void cursor_init_kernel(int* __restrict__ cursor, int nbuk, int cap) {
    int i = blockIdx.x * blockDim.x + threadIdx.x;
    if (i < nbuk) cursor[i] = i * cap;
}

// bin edges by destination bucket (row>>7). Per-block LDS histogram ->
// one global cursor atomic per (block,bucket) reserving a contiguous run ->
// edges written into their run (L2 merges the 8B writes within a run).
__global__ __launch_bounds__(256) void bin_kernel(
    const int* __restrict__ ei, const float* __restrict__ ev,
    int* __restrict__ cursor, uint2* __restrict__ ecv, int E, int nbuk)
{
    __shared__ int cnt[MAXBUK];
    __shared__ int bas[MAXBUK];
    const int tid = threadIdx.x;
    const int e0 = blockIdx.x * BIN_CHUNK;
    const int e1 = min(e0 + BIN_CHUNK, E);

    for (int i = tid; i < nbuk; i += 256) cnt[i] = 0;
    __syncthreads();
    for (int e = e0 + tid; e < e1; e += 256)
        atomicAdd(&cnt[ei[e] >> 7], 1);
    __syncthreads();
    for (int i = tid; i < nbuk; i += 256) {
        int c = cnt[i];
        bas[i] = c ? atomicAdd(&cursor[i], c) : 0;
        cnt[i] = 0;
    }
    __syncthreads();
    for (int e = e0 + tid; e < e1; e += 256) {
        int r = ei[e];
        int b = r >> 7;
        int slot = atomicAdd(&cnt[b], 1);
        uint2 cv;
        cv.x = ((unsigned)ei[E + e] << 7) | (unsigned)(r & 127);
        cv.y = __float_as_uint(ev[e]);
        ecv[(size_t)bas[b] + slot] = cv;
    }
}

// one block per bucket: fp32 LDS accumulator [128 rows][128 cols], bf16 row
// gathers, conflict-free ds_add_f32, fused identity+bias writeout.
__global__ __launch_bounds__(512) void baccum_kernel(
    const uint2* __restrict__ ecv, const int* __restrict__ cursor,
    const unsigned short* __restrict__ Sb, const float* __restrict__ bias,
    float* __restrict__ out, int Nrows, int cap)
{
    __shared__ float acc[RPB * D_DIM];   // 64 KB
    const int tid  = threadIdx.x;
    const int wv   = tid >> 6;
    const int lane = tid & 63;
    const int b    = blockIdx.x;

    for (int i = tid; i < RPB * D_DIM / 4; i += 512)
        *(float4*)&acc[i * 4] = make_float4(0.f, 0.f, 0.f, 0.f);
    __syncthreads();

    const int beg = b * cap;
    const int end = cursor[b];

    for (int e4 = beg + wv * 4; e4 < end; e4 += 32) {
        if (e4 + 3 < end) {
            uint2 cv0 = ecv[e4];
            uint2 cv1 = ecv[e4 + 1];
            uint2 cv2 = ecv[e4 + 2];
            uint2 cv3 = ecv[e4 + 3];
            int rl0 = cv0.x & 127, c0 = cv0.x >> 7;
            int rl1 = cv1.x & 127, c1 = cv1.x >> 7;
            int rl2 = cv2.x & 127, c2 = cv2.x >> 7;
            int rl3 = cv3.x & 127, c3 = cv3.x >> 7;
            float v0 = __uint_as_float(cv0.y);
            float v1 = __uint_as_float(cv1.y);
            float v2 = __uint_as_float(cv2.y);
            float v3 = __uint_as_float(cv3.y);
            float s00 = bf16_to_f32(Sb[(size_t)c0 * D_DIM + lane]);
            float s01 = bf16_to_f32(Sb[(size_t)c0 * D_DIM + 64 + lane]);
            float s10 = bf16_to_f32(Sb[(size_t)c1 * D_DIM + lane]);
            float s11 = bf16_to_f32(Sb[(size_t)c1 * D_DIM + 64 + lane]);
            float s20 = bf16_to_f32(Sb[(size_t)c2 * D_DIM + lane]);
            float s21 = bf16_to_f32(Sb[(size_t)c2 * D_DIM + 64 + lane]);
            float s30 = bf16_to_f32(Sb[(size_t)c3 * D_DIM + lane]);
            float s31 = bf16_to_f32(Sb[(size_t)c3 * D_DIM + 64 + lane]);
            unsafeAtomicAdd(&acc[rl0 * D_DIM + lane],      v0 * s00);
            unsafeAtomicAdd(&acc[rl0 * D_DIM + 64 + lane], v0 * s01);
            unsafeAtomicAdd(&acc[rl1 * D_DIM + lane],      v1 * s10);
            unsafeAtomicAdd(&acc[rl1 * D_DIM + 64 + lane], v1 * s11);
            unsafeAtomicAdd(&acc[rl2 * D_DIM + lane],      v2 * s20);
            unsafeAtomicAdd(&acc[rl2 * D_DIM + 64 + lane], v2 * s21);
            unsafeAtomicAdd(&acc[rl3 * D_DIM + lane],      v3 * s30);
            unsafeAtomicAdd(&acc[rl3 * D_DIM + 64 + lane], v3 * s31);
        } else {
            for (int j = 0; j < 4; ++j) {
                int e = e4 + j;
                if (e < end) {
                    uint2 cv = ecv[e];
                    int rl = cv.x & 127, c = cv.x >> 7;
                    float v = __uint_as_float(cv.y);
                    float s0 = bf16_to_f32(Sb[(size_t)c * D_DIM + lane]);
                    float s1 = bf16_to_f32(Sb[(size_t)c * D_DIM + 64 + lane]);
                    unsafeAtomicAdd(&acc[rl * D_DIM + lane],      v * s0);
                    unsafeAtomicAdd(&acc[rl * D_DIM + 64 + lane], v * s1);
                }
            }
        }
    }
    __syncthreads();

    const int r0 = b * RPB;
    for (int idx = tid; idx < RPB * (D_DIM / 4); idx += 512) {
        int i = idx >> 5;
        int q = idx & 31;
        int r = r0 + i;
        if (r >= Nrows) continue;
        float4 a = *(float4*)&acc[i * D_DIM + q * 4];
        const unsigned short* sp = &Sb[(size_t)r * D_DIM + q * 4];
        float4 bv = *(const float4*)&bias[q * 4];
        float4 o;
        o.x = a.x + bf16_to_f32(sp[0]) + bv.x;
        o.y = a.y + bf16_to_f32(sp[1]) + bv.y;
        o.z = a.z + bf16_to_f32(sp[2]) + bv.z;
        o.w = a.w + bf16_to_f32(sp[3]) + bv.w;
        *(float4*)&out[(size_t)r * D_DIM + q * 4] = o;
    }
}

extern "C" void kernel_launch(void* const* d_in, const int* in_sizes, int n_in,
                              void* d_out, int out_size, void* d_ws, size_t ws_size,
                              hipStream_t stream) {
    const float* feature = (const float*)d_in[0];
    const float* W       = (const float*)d_in[1];
    const float* bias    = (const float*)d_in[2];
    const float* ev      = (const float*)d_in[3];
    const int*   ei      = (const int*)d_in[4];
    float* out = (float*)d_out;

    const int N = in_sizes[0] / F_DIM;   // 100000
    const int E = in_sizes[3];           // 1600000
    const int nbuk = (N + RPB - 1) / RPB;            // 782
    int cap = (E + nbuk - 1) / nbuk;
    cap = cap + cap / 4 + 256;                       // ~2813, >>12 sigma slack

    char* ws = (char*)d_ws;
    size_t cur = 0;
    auto alloc = [&](size_t bytes) -> void* {
        void* p = ws + cur;
        cur = (cur + bytes + 255) & ~(size_t)255;
        return p;
    };
    unsigned short* Sb     = (unsigned short*)alloc((size_t)N * D_DIM * 2);
    unsigned short* Wt     = (unsigned short*)alloc((size_t)D_DIM * F_DIM * 2);
    int*            cursor = (int*)alloc((size_t)nbuk * 4);
    uint2*          ecv    = (uint2*)alloc(((size_t)nbuk * cap + BIN_CHUNK) * 8);
    (void)ws_size;

    wt_kernel<<<(F_DIM * D_DIM) / 256, 256, 0, stream>>>(W, Wt);
    gemm_relu_pipe<<<(N + 127) / 128, 256, 0, stream>>>(feature, Wt, Sb, N);
    cursor_init_kernel<<<(nbuk + 255) / 256, 256, 0, stream>>>(cursor, nbuk, cap);
    bin_kernel<<<(E + BIN_CHUNK - 1) / BIN_CHUNK, 256, 0, stream>>>(ei, ev, cursor, ecv, E, nbuk);
    baccum_kernel<<<nbuk, 512, 0, stream>>>(ecv, cursor, Sb, bias, out, N, cap);
}

// Round 6
// 221.997 us; speedup vs baseline: 6.5464x; 6.5464x over previous
//
#include <hip/hip_runtime.h>
#include <hip/hip_bf16.h>

typedef __attribute__((ext_vector_type(8))) __bf16 bf16x8;
typedef __attribute__((ext_vector_type(4))) float f32x4;

#define F_DIM 512
#define D_DIM 128
#define RPB 128            // rows per bucket (bucket = row >> 7)
#define MAXBUK 1024
#define BIN_CHUNK 8192

__device__ __forceinline__ unsigned short f32_to_bf16_rn(float x) {
    union { float f; unsigned u; } v; v.f = x;
    unsigned u = v.u;
    unsigned rounded = u + 0x7fffu + ((u >> 16) & 1u);
    return (unsigned short)(rounded >> 16);
}
__device__ __forceinline__ float bf16_to_f32(unsigned short u) {
    return __uint_as_float((unsigned)u << 16);
}

// W [512][128] f32 -> Wt [128][512] bf16 (transposed, k-contiguous)
__global__ void wt_kernel(const float* __restrict__ W, unsigned short* __restrict__ Wt) {
    int idx = blockIdx.x * blockDim.x + threadIdx.x;   // 65536 total
    int n = idx >> 9;
    int k = idx & 511;
    Wt[idx] = f32_to_bf16_rn(W[k * D_DIM + n]);
}

// support = relu(feature @ W) -> bf16. 128x128 tile, BK=32, reg-staged +
// LDS double-buffer, one barrier per K-step.
__global__ __launch_bounds__(256) void gemm_relu_pipe(
    const float* __restrict__ A,
    const unsigned short* __restrict__ Bt,
    unsigned short* __restrict__ Sb,
    int Nrows)
{
    __shared__ unsigned short Al[2 * 128 * 40];
    __shared__ unsigned short Bl[2 * 128 * 40];

    const int tid  = threadIdx.x;
    const int wave = tid >> 6;
    const int lane = tid & 63;
    const int g    = lane >> 4;
    const int r16  = lane & 15;
    const int m0   = blockIdx.x * 128;

    const int srow = tid >> 1;
    const int kh   = tid & 1;
    int arow = m0 + srow;
    if (arow >= Nrows) arow = Nrows - 1;
    const float*          aptr = A  + (size_t)arow * F_DIM + kh * 16;
    const unsigned short* bptr = Bt + (size_t)srow * F_DIM + kh * 16;
    const int woff = srow * 40 + kh * 16;

    float4 ar0, ar1, ar2, ar3;
    uint4  br0, br1;

    auto loadAB = [&](int ks) {
        const float4* pa = (const float4*)(aptr + ks * 32);
        ar0 = pa[0]; ar1 = pa[1]; ar2 = pa[2]; ar3 = pa[3];
        const uint4* pb = (const uint4*)(bptr + ks * 32);
        br0 = pb[0]; br1 = pb[1];
    };
    auto storeAB = [&](int buf) {
        union { uint4 q[2]; __bf16 h[16]; } u;
        u.h[0]=(__bf16)ar0.x;  u.h[1]=(__bf16)ar0.y;  u.h[2]=(__bf16)ar0.z;  u.h[3]=(__bf16)ar0.w;
        u.h[4]=(__bf16)ar1.x;  u.h[5]=(__bf16)ar1.y;  u.h[6]=(__bf16)ar1.z;  u.h[7]=(__bf16)ar1.w;
        u.h[8]=(__bf16)ar2.x;  u.h[9]=(__bf16)ar2.y;  u.h[10]=(__bf16)ar2.z; u.h[11]=(__bf16)ar2.w;
        u.h[12]=(__bf16)ar3.x; u.h[13]=(__bf16)ar3.y; u.h[14]=(__bf16)ar3.z; u.h[15]=(__bf16)ar3.w;
        unsigned short* aw = Al + buf * 5120 + woff;
        unsigned short* bw = Bl + buf * 5120 + woff;
        *(uint4*)aw       = u.q[0];
        *(uint4*)(aw + 8) = u.q[1];
        *(uint4*)bw       = br0;
        *(uint4*)(bw + 8) = br1;
    };

    f32x4 acc[2][8];
#pragma unroll
    for (int i = 0; i < 2; ++i)
#pragma unroll
        for (int j = 0; j < 8; ++j) acc[i][j] = (f32x4)0.0f;

    loadAB(0);
    storeAB(0);
    __syncthreads();

#pragma unroll
    for (int ks = 0; ks < 16; ++ks) {
        const int cur = ks & 1;
        if (ks < 15) loadAB(ks + 1);

        const unsigned short* Ab = Al + cur * 5120;
        const unsigned short* Bb = Bl + cur * 5120;
        bf16x8 af0 = *(const bf16x8*)&Ab[(wave * 32 +      r16) * 40 + g * 8];
        bf16x8 af1 = *(const bf16x8*)&Ab[(wave * 32 + 16 + r16) * 40 + g * 8];
#pragma unroll
        for (int nf = 0; nf < 8; ++nf) {
            bf16x8 bf = *(const bf16x8*)&Bb[(nf * 16 + r16) * 40 + g * 8];
            acc[0][nf] = __builtin_amdgcn_mfma_f32_16x16x32_bf16(af0, bf, acc[0][nf], 0, 0, 0);
            acc[1][nf] = __builtin_amdgcn_mfma_f32_16x16x32_bf16(af1, bf, acc[1][nf], 0, 0, 0);
        }

        if (ks < 15) storeAB(cur ^ 1);
        __syncthreads();
    }

#pragma unroll
    for (int mf = 0; mf < 2; ++mf) {
#pragma unroll
        for (int nf = 0; nf < 8; ++nf) {
#pragma unroll
            for (int r = 0; r < 4; ++r) {
                int row = m0 + wave * 32 + mf * 16 + g * 4 + r;
                if (row < Nrows) {
                    float v = acc[mf][nf][r];
                    Sb[(size_t)row * D_DIM + nf * 16 + r16] = f32_to_bf16_rn(v > 0.f ? v : 0.f);
                }
            }
        }
    }
}

// cursor[b] = b * cap
__global__ void cursor_init_kernel(int* __restrict__ cursor, int nbuk, int cap) {
    int i = blockIdx.x * blockDim.x + threadIdx.x;
    if (i < nbuk) cursor[i] = i * cap;
}

// bin edges by destination bucket (row>>7). Per-block LDS histogram ->
// one global cursor atomic per (block,bucket) reserving a contiguous run ->
// edges written into their run (L2 merges the 8B writes within a run).
__global__ __launch_bounds__(256) void bin_kernel(
    const int* __restrict__ ei, const float* __restrict__ ev,
    int* __restrict__ cursor, uint2* __restrict__ ecv, int E, int nbuk)
{
    __shared__ int cnt[MAXBUK];
    __shared__ int bas[MAXBUK];
    const int tid = threadIdx.x;
    const int e0 = blockIdx.x * BIN_CHUNK;
    const int e1 = min(e0 + BIN_CHUNK, E);

    for (int i = tid; i < nbuk; i += 256) cnt[i] = 0;
    __syncthreads();
    for (int e = e0 + tid; e < e1; e += 256)
        atomicAdd(&cnt[ei[e] >> 7], 1);
    __syncthreads();
    for (int i = tid; i < nbuk; i += 256) {
        int c = cnt[i];
        bas[i] = c ? atomicAdd(&cursor[i], c) : 0;
        cnt[i] = 0;
    }
    __syncthreads();
    for (int e = e0 + tid; e < e1; e += 256) {
        int r = ei[e];
        int b = r >> 7;
        int slot = atomicAdd(&cnt[b], 1);
        uint2 cv;
        cv.x = ((unsigned)ei[E + e] << 7) | (unsigned)(r & 127);
        cv.y = __float_as_uint(ev[e]);
        ecv[(size_t)bas[b] + slot] = cv;
    }
}

// one block per bucket: counting-sort the bucket's edges by row (128-way),
// all traffic within a ~16-22 KB L2-hot region. Publishes rowoff/rowcnt.
__global__ __launch_bounds__(256) void bsort_kernel(
    const uint2* __restrict__ ecv, const int* __restrict__ cursor,
    uint2* __restrict__ ecv2, int* __restrict__ rowoff, int* __restrict__ rowcnt,
    int cap, int Nrows)
{
    __shared__ int cnt[RPB];
    __shared__ int base[RPB];
    const int tid = threadIdx.x;
    const int b   = blockIdx.x;
    const int beg = b * cap;
    const int end = cursor[b];

    if (tid < RPB) cnt[tid] = 0;
    __syncthreads();
    for (int i = beg + tid; i < end; i += 256)
        atomicAdd(&cnt[ecv[i].x & 127], 1);
    __syncthreads();
    // exclusive scan of 128 counts by wave 0 (two 64-chunks + carry)
    if (tid < 64) {
        int carry = 0;
#pragma unroll
        for (int c = 0; c < 2; ++c) {
            int idx = c * 64 + tid;
            int v = cnt[idx];
            int orig = v;
            for (int d = 1; d < 64; d <<= 1) {
                int t = __shfl_up(v, d, 64);
                if (tid >= d) v += t;
            }
            base[idx] = carry + v - orig;
            carry += __shfl(v, 63, 64);
        }
    }
    __syncthreads();
    if (tid < RPB) {
        int r = b * RPB + tid;
        if (r < Nrows) {
            rowoff[r] = beg + base[tid];
            rowcnt[r] = cnt[tid];
        }
        cnt[tid] = 0;   // reuse as per-row cursor
    }
    __syncthreads();
    for (int i = beg + tid; i < end; i += 256) {
        uint2 cv = ecv[i];
        int rl = cv.x & 127;
        int slot = atomicAdd(&cnt[rl], 1);
        ecv2[(size_t)beg + base[rl] + slot] = cv;
    }
}

// one wave per row: acc = sum(val * Sb[col]) (bf16 gathers, 256B/edge);
// out = acc + Sb[row] + bias. Register accumulate, no atomics.
__global__ __launch_bounds__(256) void accum_kernel(
    const uint2* __restrict__ ecv2, const int* __restrict__ rowoff,
    const int* __restrict__ rowcnt, const unsigned short* __restrict__ Sb,
    const float* __restrict__ bias, float* __restrict__ out, int n)
{
    int wid = (blockIdx.x * 256 + threadIdx.x) >> 6;
    if (wid >= n) return;
    int lane = threadIdx.x & 63;
    int c2 = lane * 2;

    int start = rowoff[wid];
    int end   = start + rowcnt[wid];

    float ax = 0.f, ay = 0.f;
    int i = start;
    for (; i + 3 < end; i += 4) {
        uint2 cv0 = ecv2[i];
        uint2 cv1 = ecv2[i + 1];
        uint2 cv2 = ecv2[i + 2];
        uint2 cv3 = ecv2[i + 3];
        ushort2 s0 = *(const ushort2*)&Sb[(size_t)(cv0.x >> 7) * D_DIM + c2];
        ushort2 s1 = *(const ushort2*)&Sb[(size_t)(cv1.x >> 7) * D_DIM + c2];
        ushort2 s2 = *(const ushort2*)&Sb[(size_t)(cv2.x >> 7) * D_DIM + c2];
        ushort2 s3 = *(const ushort2*)&Sb[(size_t)(cv3.x >> 7) * D_DIM + c2];
        float v0 = __uint_as_float(cv0.y);
        float v1 = __uint_as_float(cv1.y);
        float v2 = __uint_as_float(cv2.y);
        float v3 = __uint_as_float(cv3.y);
        ax += v0 * bf16_to_f32(s0.x) + v1 * bf16_to_f32(s1.x)
            + v2 * bf16_to_f32(s2.x) + v3 * bf16_to_f32(s3.x);
        ay += v0 * bf16_to_f32(s0.y) + v1 * bf16_to_f32(s1.y)
            + v2 * bf16_to_f32(s2.y) + v3 * bf16_to_f32(s3.y);
    }
    for (; i < end; ++i) {
        uint2 cv = ecv2[i];
        ushort2 s = *(const ushort2*)&Sb[(size_t)(cv.x >> 7) * D_DIM + c2];
        float v = __uint_as_float(cv.y);
        ax += v * bf16_to_f32(s.x);
        ay += v * bf16_to_f32(s.y);
    }

    ushort2 so = *(const ushort2*)&Sb[(size_t)wid * D_DIM + c2];
    float2 b = *(const float2*)&bias[c2];
    float2 o;
    o.x = ax + bf16_to_f32(so.x) + b.x;
    o.y = ay + bf16_to_f32(so.y) + b.y;
    *(float2*)&out[(size_t)wid * D_DIM + c2] = o;
}

extern "C" void kernel_launch(void* const* d_in, const int* in_sizes, int n_in,
                              void* d_out, int out_size, void* d_ws, size_t ws_size,
                              hipStream_t stream) {
    const float* feature = (const float*)d_in[0];
    const float* W       = (const float*)d_in[1];
    const float* bias    = (const float*)d_in[2];
    const float* ev      = (const float*)d_in[3];
    const int*   ei      = (const int*)d_in[4];
    float* out = (float*)d_out;

    const int N = in_sizes[0] / F_DIM;   // 100000
    const int E = in_sizes[3];           // 1600000
    const int nbuk = (N + RPB - 1) / RPB;            // 782
    int cap = (E + nbuk - 1) / nbuk;
    cap = cap + cap / 4 + 256;                       // ~2813, >>12 sigma slack

    char* ws = (char*)d_ws;
    size_t cur = 0;
    auto alloc = [&](size_t bytes) -> void* {
        void* p = ws + cur;
        cur = (cur + bytes + 255) & ~(size_t)255;
        return p;
    };
    unsigned short* Sb     = (unsigned short*)alloc((size_t)N * D_DIM * 2);
    unsigned short* Wt     = (unsigned short*)alloc((size_t)D_DIM * F_DIM * 2);
    int*            cursor = (int*)alloc((size_t)nbuk * 4);
    int*            rowoff = (int*)alloc((size_t)N * 4);
    int*            rowcnt = (int*)alloc((size_t)N * 4);
    uint2*          ecv    = (uint2*)alloc(((size_t)nbuk * cap + BIN_CHUNK) * 8);
    uint2*          ecv2   = (uint2*)alloc(((size_t)nbuk * cap + BIN_CHUNK) * 8);
    (void)ws_size;

    wt_kernel<<<(F_DIM * D_DIM) / 256, 256, 0, stream>>>(W, Wt);
    gemm_relu_pipe<<<(N + 127) / 128, 256, 0, stream>>>(feature, Wt, Sb, N);
    cursor_init_kernel<<<(nbuk + 255) / 256, 256, 0, stream>>>(cursor, nbuk, cap);
    bin_kernel<<<(E + BIN_CHUNK - 1) / BIN_CHUNK, 256, 0, stream>>>(ei, ev, cursor, ecv, E, nbuk);
    bsort_kernel<<<nbuk, 256, 0, stream>>>(ecv, cursor, ecv2, rowoff, rowcnt, cap, N);
    accum_kernel<<<(N + 3) / 4, 256, 0, stream>>>(ecv2, rowoff, rowcnt, Sb, bias, out, N);
}

// Round 7
// 220.104 us; speedup vs baseline: 6.6027x; 1.0086x over previous
//
#include <hip/hip_runtime.h>
#include <hip/hip_bf16.h>

typedef __attribute__((ext_vector_type(8))) __bf16 bf16x8;
typedef __attribute__((ext_vector_type(4))) float f32x4;

#define F_DIM 512
#define D_DIM 128
#define RPB 128            // rows per bucket (bucket = row >> 7)
#define MAXBUK 1024
#define BIN_CHUNK 8192

__device__ __forceinline__ unsigned short f32_to_bf16_rn(float x) {
    union { float f; unsigned u; } v; v.f = x;
    unsigned u = v.u;
    unsigned rounded = u + 0x7fffu + ((u >> 16) & 1u);
    return (unsigned short)(rounded >> 16);
}
__device__ __forceinline__ float bf16_to_f32(unsigned short u) {
    return __uint_as_float((unsigned)u << 16);
}

// W [512][128] f32 -> Wt [128][512] bf16 (transposed, k-contiguous)
__global__ void wt_kernel(const float* __restrict__ W, unsigned short* __restrict__ Wt) {
    int idx = blockIdx.x * blockDim.x + threadIdx.x;   // 65536 total
    int n = idx >> 9;
    int k = idx & 511;
    Wt[idx] = f32_to_bf16_rn(W[k * D_DIM + n]);
}

// support = relu(feature @ W) -> bf16. 64(M)x128(N) tile, BK=32, 4 waves,
// each wave owns 16 rows. Reg-staged + LDS double-buffer, one barrier/K-step.
// 1563 blocks -> 76% wave occupancy (vs 38% at 128-row tiles).
__global__ __launch_bounds__(256) void gemm_relu_pipe(
    const float* __restrict__ A,
    const unsigned short* __restrict__ Bt,
    unsigned short* __restrict__ Sb,
    int Nrows)
{
    __shared__ unsigned short Al[2 * 64 * 40];    // 10 KB, [buf][row][k] pad 40
    __shared__ unsigned short Bl[2 * 128 * 40];   // 20 KB

    const int tid  = threadIdx.x;
    const int wave = tid >> 6;
    const int lane = tid & 63;
    const int g    = lane >> 4;
    const int r16  = lane & 15;
    const int m0   = blockIdx.x * 64;

    // A staging: thread covers row sar (0..63), k-quarter skq (8 f32 = 32 B)
    const int sar = tid >> 2;
    const int skq = tid & 3;
    int arow = m0 + sar;
    if (arow >= Nrows) arow = Nrows - 1;           // duplicate-safe; stores guarded
    const float* aptr = A + (size_t)arow * F_DIM + skq * 8;
    const int awoff = sar * 40 + skq * 8;

    // B staging: thread covers Wt row sbr (0..127), k-half skh (16 bf16 = 32 B)
    const int sbr = tid >> 1;
    const int skh = tid & 1;
    const unsigned short* bptr = Bt + (size_t)sbr * F_DIM + skh * 16;
    const int bwoff = sbr * 40 + skh * 16;

    float4 ar0, ar1;
    uint4  br0, br1;

    auto loadAB = [&](int ks) {
        const float4* pa = (const float4*)(aptr + ks * 32);
        ar0 = pa[0]; ar1 = pa[1];
        const uint4* pb = (const uint4*)(bptr + ks * 32);
        br0 = pb[0]; br1 = pb[1];
    };
    auto storeAB = [&](int buf) {
        union { uint4 q; __bf16 h[8]; } u;
        u.h[0]=(__bf16)ar0.x; u.h[1]=(__bf16)ar0.y; u.h[2]=(__bf16)ar0.z; u.h[3]=(__bf16)ar0.w;
        u.h[4]=(__bf16)ar1.x; u.h[5]=(__bf16)ar1.y; u.h[6]=(__bf16)ar1.z; u.h[7]=(__bf16)ar1.w;
        *(uint4*)&Al[buf * 2560 + awoff] = u.q;
        unsigned short* bw = &Bl[buf * 5120 + bwoff];
        *(uint4*)bw       = br0;
        *(uint4*)(bw + 8) = br1;
    };

    f32x4 acc[8];
#pragma unroll
    for (int j = 0; j < 8; ++j) acc[j] = (f32x4)0.0f;

    loadAB(0);
    storeAB(0);
    __syncthreads();

#pragma unroll
    for (int ks = 0; ks < 16; ++ks) {
        const int cur = ks & 1;
        if (ks < 15) loadAB(ks + 1);

        const unsigned short* Ab = Al + cur * 2560;
        const unsigned short* Bb = Bl + cur * 5120;
        bf16x8 af = *(const bf16x8*)&Ab[(wave * 16 + r16) * 40 + g * 8];
#pragma unroll
        for (int nf = 0; nf < 8; ++nf) {
            bf16x8 bf = *(const bf16x8*)&Bb[(nf * 16 + r16) * 40 + g * 8];
            acc[nf] = __builtin_amdgcn_mfma_f32_16x16x32_bf16(af, bf, acc[nf], 0, 0, 0);
        }

        if (ks < 15) storeAB(cur ^ 1);
        __syncthreads();
    }

#pragma unroll
    for (int nf = 0; nf < 8; ++nf) {
#pragma unroll
        for (int r = 0; r < 4; ++r) {
            int row = m0 + wave * 16 + g * 4 + r;
            if (row < Nrows) {
                float v = acc[nf][r];
                Sb[(size_t)row * D_DIM + nf * 16 + r16] = f32_to_bf16_rn(v > 0.f ? v : 0.f);
            }
        }
    }
}

// cursor[b] = b * cap
__global__ void cursor_init_kernel(int* __restrict__ cursor, int nbuk, int cap) {
    int i = blockIdx.x * blockDim.x + threadIdx.x;
    if (i < nbuk) cursor[i] = i * cap;
}

// bin edges by destination bucket (row>>7). Per-block LDS histogram ->
// one global cursor atomic per (block,bucket) reserving a contiguous run ->
// edges written into their run (L2 merges the 8B writes within a run).
__global__ __launch_bounds__(256) void bin_kernel(
    const int* __restrict__ ei, const float* __restrict__ ev,
    int* __restrict__ cursor, uint2* __restrict__ ecv, int E, int nbuk)
{
    __shared__ int cnt[MAXBUK];
    __shared__ int bas[MAXBUK];
    const int tid = threadIdx.x;
    const int e0 = blockIdx.x * BIN_CHUNK;
    const int e1 = min(e0 + BIN_CHUNK, E);

    for (int i = tid; i < nbuk; i += 256) cnt[i] = 0;
    __syncthreads();
    for (int e = e0 + tid; e < e1; e += 256)
        atomicAdd(&cnt[ei[e] >> 7], 1);
    __syncthreads();
    for (int i = tid; i < nbuk; i += 256) {
        int c = cnt[i];
        bas[i] = c ? atomicAdd(&cursor[i], c) : 0;
        cnt[i] = 0;
    }
    __syncthreads();
    for (int e = e0 + tid; e < e1; e += 256) {
        int r = ei[e];
        int b = r >> 7;
        int slot = atomicAdd(&cnt[b], 1);
        uint2 cv;
        cv.x = ((unsigned)ei[E + e] << 7) | (unsigned)(r & 127);
        cv.y = __float_as_uint(ev[e]);
        ecv[(size_t)bas[b] + slot] = cv;
    }
}

// one block per bucket: counting-sort the bucket's edges by row (128-way),
// all traffic within a ~16-22 KB L2-hot region. Publishes rowoff/rowcnt.
__global__ __launch_bounds__(256) void bsort_kernel(
    const uint2* __restrict__ ecv, const int* __restrict__ cursor,
    uint2* __restrict__ ecv2, int* __restrict__ rowoff, int* __restrict__ rowcnt,
    int cap, int Nrows)
{
    __shared__ int cnt[RPB];
    __shared__ int base[RPB];
    const int tid = threadIdx.x;
    const int b   = blockIdx.x;
    const int beg = b * cap;
    const int end = cursor[b];

    if (tid < RPB) cnt[tid] = 0;
    __syncthreads();
    for (int i = beg + tid; i < end; i += 256)
        atomicAdd(&cnt[ecv[i].x & 127], 1);
    __syncthreads();
    // exclusive scan of 128 counts by wave 0 (two 64-chunks + carry)
    if (tid < 64) {
        int carry = 0;
#pragma unroll
        for (int c = 0; c < 2; ++c) {
            int idx = c * 64 + tid;
            int v = cnt[idx];
            int orig = v;
            for (int d = 1; d < 64; d <<= 1) {
                int t = __shfl_up(v, d, 64);
                if (tid >= d) v += t;
            }
            base[idx] = carry + v - orig;
            carry += __shfl(v, 63, 64);
        }
    }
    __syncthreads();
    if (tid < RPB) {
        int r = b * RPB + tid;
        if (r < Nrows) {
            rowoff[r] = beg + base[tid];
            rowcnt[r] = cnt[tid];
        }
        cnt[tid] = 0;   // reuse as per-row cursor
    }
    __syncthreads();
    for (int i = beg + tid; i < end; i += 256) {
        uint2 cv = ecv[i];
        int rl = cv.x & 127;
        int slot = atomicAdd(&cnt[rl], 1);
        ecv2[(size_t)beg + base[rl] + slot] = cv;
    }
}

// one wave per row: acc = sum(val * Sb[col]) (bf16 gathers, 256B/edge);
// out = acc + Sb[row] + bias. Register accumulate, no atomics.
__global__ __launch_bounds__(256) void accum_kernel(
    const uint2* __restrict__ ecv2, const int* __restrict__ rowoff,
    const int* __restrict__ rowcnt, const unsigned short* __restrict__ Sb,
    const float* __restrict__ bias, float* __restrict__ out, int n)
{
    int wid = (blockIdx.x * 256 + threadIdx.x) >> 6;
    if (wid >= n) return;
    int lane = threadIdx.x & 63;
    int c2 = lane * 2;

    int start = rowoff[wid];
    int end   = start + rowcnt[wid];

    float ax = 0.f, ay = 0.f;
    int i = start;
    for (; i + 3 < end; i += 4) {
        uint2 cv0 = ecv2[i];
        uint2 cv1 = ecv2[i + 1];
        uint2 cv2 = ecv2[i + 2];
        uint2 cv3 = ecv2[i + 3];
        ushort2 s0 = *(const ushort2*)&Sb[(size_t)(cv0.x >> 7) * D_DIM + c2];
        ushort2 s1 = *(const ushort2*)&Sb[(size_t)(cv1.x >> 7) * D_DIM + c2];
        ushort2 s2 = *(const ushort2*)&Sb[(size_t)(cv2.x >> 7) * D_DIM + c2];
        ushort2 s3 = *(const ushort2*)&Sb[(size_t)(cv3.x >> 7) * D_DIM + c2];
        float v0 = __uint_as_float(cv0.y);
        float v1 = __uint_as_float(cv1.y);
        float v2 = __uint_as_float(cv2.y);
        float v3 = __uint_as_float(cv3.y);
        ax += v0 * bf16_to_f32(s0.x) + v1 * bf16_to_f32(s1.x)
            + v2 * bf16_to_f32(s2.x) + v3 * bf16_to_f32(s3.x);
        ay += v0 * bf16_to_f32(s0.y) + v1 * bf16_to_f32(s1.y)
            + v2 * bf16_to_f32(s2.y) + v3 * bf16_to_f32(s3.y);
    }
    for (; i < end; ++i) {
        uint2 cv = ecv2[i];
        ushort2 s = *(const ushort2*)&Sb[(size_t)(cv.x >> 7) * D_DIM + c2];
        float v = __uint_as_float(cv.y);
        ax += v * bf16_to_f32(s.x);
        ay += v * bf16_to_f32(s.y);
    }

    ushort2 so = *(const ushort2*)&Sb[(size_t)wid * D_DIM + c2];
    float2 b = *(const float2*)&bias[c2];
    float2 o;
    o.x = ax + bf16_to_f32(so.x) + b.x;
    o.y = ay + bf16_to_f32(so.y) + b.y;
    *(float2*)&out[(size_t)wid * D_DIM + c2] = o;
}

extern "C" void kernel_launch(void* const* d_in, const int* in_sizes, int n_in,
                              void* d_out, int out_size, void* d_ws, size_t ws_size,
                              hipStream_t stream) {
    const float* feature = (const float*)d_in[0];
    const float* W       = (const float*)d_in[1];
    const float* bias    = (const float*)d_in[2];
    const float* ev      = (const float*)d_in[3];
    const int*   ei      = (const int*)d_in[4];
    float* out = (float*)d_out;

    const int N = in_sizes[0] / F_DIM;   // 100000
    const int E = in_sizes[3];           // 1600000
    const int nbuk = (N + RPB - 1) / RPB;            // 782
    int cap = (E + nbuk - 1) / nbuk;
    cap = cap + cap / 4 + 256;                       // ~2813, >>12 sigma slack

    char* ws = (char*)d_ws;
    size_t cur = 0;
    auto alloc = [&](size_t bytes) -> void* {
        void* p = ws + cur;
        cur = (cur + bytes + 255) & ~(size_t)255;
        return p;
    };
    unsigned short* Sb     = (unsigned short*)alloc((size_t)N * D_DIM * 2);
    unsigned short* Wt     = (unsigned short*)alloc((size_t)D_DIM * F_DIM * 2);
    int*            cursor = (int*)alloc((size_t)nbuk * 4);
    int*            rowoff = (int*)alloc((size_t)N * 4);
    int*            rowcnt = (int*)alloc((size_t)N * 4);
    uint2*          ecv    = (uint2*)alloc(((size_t)nbuk * cap + BIN_CHUNK) * 8);
    uint2*          ecv2   = (uint2*)alloc(((size_t)nbuk * cap + BIN_CHUNK) * 8);
    (void)ws_size;

    wt_kernel<<<(F_DIM * D_DIM) / 256, 256, 0, stream>>>(W, Wt);
    gemm_relu_pipe<<<(N + 63) / 64, 256, 0, stream>>>(feature, Wt, Sb, N);
    cursor_init_kernel<<<(nbuk + 255) / 256, 256, 0, stream>>>(cursor, nbuk, cap);
    bin_kernel<<<(E + BIN_CHUNK - 1) / BIN_CHUNK, 256, 0, stream>>>(ei, ev, cursor, ecv, E, nbuk);
    bsort_kernel<<<nbuk, 256, 0, stream>>>(ecv, cursor, ecv2, rowoff, rowcnt, cap, N);
    accum_kernel<<<(N + 3) / 4, 256, 0, stream>>>(ecv2, rowoff, rowcnt, Sb, bias, out, N);
}